// Round 13
// baseline (93.076 us; speedup 1.0000x reference)
//
#include <hip/hip_runtime.h>

#define H 65536
#define CIN 64
#define COUT 128
#define NK 27
#define KTOT (NK*CIN)   // 1728
#define NBLK 256        // points per block; 16 waves = 4 wo x 4 wn (32o x 64n)
#define NTHR 1024
#define NBLOCKS (H/NBLK) // 256

typedef unsigned short u16;
typedef unsigned int   u32;
typedef __attribute__((ext_vector_type(8))) short short8;   // 8 bf16 (MFMA frag)
typedef __attribute__((ext_vector_type(4))) float f32x4;    // MFMA acc
typedef __attribute__((ext_vector_type(4))) unsigned int u32x4;

__device__ __forceinline__ u16 f2bf(float f) {
    u32 u = __float_as_uint(f);
    u = (u + 0x7FFFu + ((u >> 16) & 1u)) >> 16;   // RNE
    return (u16)u;
}

// ---------------------------------------------------------------------------
// Kernel 1a: x (64 x 65536 f32, c-major) -> x_t (65536 x 64 bf16, point-major)
__global__ __launch_bounds__(256) void transpose_x(const float* __restrict__ x,
                                                   u16* __restrict__ xt) {
    const int h = blockIdx.x * 256 + threadIdx.x;
    u32 pk[32];
#pragma unroll
    for (int cp = 0; cp < 32; ++cp) {
        float f0 = x[(2 * cp)     * H + h];
        float f1 = x[(2 * cp + 1) * H + h];
        pk[cp] = (u32)f2bf(f0) | ((u32)f2bf(f1) << 16);
    }
    u32x4* dst = (u32x4*)(xt + (size_t)h * CIN);
#pragma unroll
    for (int i = 0; i < 8; ++i)
        dst[i] = *(u32x4*)&pk[i * 4];
}

// ---------------------------------------------------------------------------
// Kernel 1b: w (128 x 64 x 27 f32) -> wb[o][k*64+c] bf16. Also zeroes BN sums.
__global__ __launch_bounds__(256) void conv_w(const float* __restrict__ w,
                                              u16* __restrict__ wb,
                                              float* __restrict__ sums) {
    const int tid = blockIdx.x * 256 + threadIdx.x;
    if (blockIdx.x == 0) sums[threadIdx.x] = 0.f;   // sum[128], sumsq[128]
    if (tid < COUT * KTOT) {
        const int o = tid / KTOT;
        const int rem = tid - o * KTOT;
        const int k = rem >> 6;
        const int c = rem & 63;
        wb[tid] = f2bf(w[o * KTOT + c * NK + k]);
    }
}

// ---------------------------------------------------------------------------
// Kernel 2: R12 with HALVED LDS read amplification: 16 waves = 4 wo-groups
// (32o each) x 4 wn (64n each) instead of 8x2. B tile re-read by 4 groups
// not 8: per-CU LDS traffic 7.8MB -> 4.3MB (the ~38us pipe floor -> ~20us).
// Gather/pipeline/swizzle/line-count identical to R12 (clean A/B).
__global__ __launch_bounds__(NTHR, 4) void conv_mfma(const u16* __restrict__ xt,
                                                     const u16* __restrict__ wb,
                                                     const int* __restrict__ neigh,
                                                     float* __restrict__ out,
                                                     float* __restrict__ part) {
    __shared__ __align__(16) u16 sB[2][NBLK * CIN];  // 2 x 32 KB, XOR-swizzled
    __shared__ u16 sIdx[NBLK * NK];                  // 13824 B (reused as f32 red)

    const int tid  = threadIdx.x;
    const int lane = tid & 63;
    const int w    = tid >> 6;        // wave 0..15
    const int wo   = w >> 2;          // o-group 0..3 (32 o each)
    const int wn   = w & 3;           // n-group 0..3 (64 n each)
    const int n0   = blockIdx.x * NBLK;

    for (int i = tid; i < NBLK * NK; i += NTHR)
        sIdx[i] = (u16)neigh[n0 * NK + i];
    __syncthreads();                   // once, before the pipeline

    const int r16 = lane & 15;
    const int q   = lane >> 4;        // 0..3
    const int kc  = q * 8;
    const int pl  = lane >> 3;        // 0..7 row-within-8
    const int cl  = lane & 7;         // 16B chunk within 128B row

    f32x4 acc[2][4] = {};             // [o-frag][n-frag]

    u32x4  rg[2][2];                  // gather regs: g(k) in rg[k&1][it]
    short8 af[2][2][2];               // A regs: A(k) in af[k&1][f][hh]

#define GATHER(K)                                                            \
    { _Pragma("unroll") for (int it = 0; it < 2; ++it) {                     \
        const int p_ = w * 16 + it * 8 + pl;                                 \
        const int row_ = sIdx[p_ * NK + (K)];                                \
        rg[(K) & 1][it] =                                                    \
            *(const u32x4*)(xt + (size_t)(u32)row_ * 64 + cl * 8); } }
#define WRITEB(K)                                                            \
    { _Pragma("unroll") for (int it = 0; it < 2; ++it) {                     \
        const int p_ = w * 16 + it * 8 + pl;                                 \
        *(u32x4*)(&sB[(K) & 1][p_ * 64 + ((cl ^ pl) * 8)]) = rg[(K) & 1][it]; } }
#define A_LOAD(K)                                                            \
    { _Pragma("unroll") for (int f = 0; f < 2; ++f)                          \
      _Pragma("unroll") for (int hh = 0; hh < 2; ++hh) {                     \
        const int o_ = wo * 32 + f * 16 + r16;                               \
        af[(K) & 1][f][hh] = *(const short8*)(wb + (size_t)o_ * KTOT +       \
                                              (K) * CIN + hh * 32 + kc); } }
#define MFMA_STEP(K)                                                         \
    { _Pragma("unroll") for (int hh = 0; hh < 2; ++hh) {                     \
        short8 bfr[4];                                                       \
        _Pragma("unroll") for (int nf = 0; nf < 4; ++nf) {                   \
            const int p_ = wn * 64 + nf * 16 + r16;                          \
            const int sl_ = (hh * 4 + q) ^ (p_ & 7);                         \
            bfr[nf] = *(const short8*)(&sB[(K) & 1][p_ * 64 + sl_ * 8]);     \
        }                                                                    \
        _Pragma("unroll") for (int f = 0; f < 2; ++f)                        \
        _Pragma("unroll") for (int nf = 0; nf < 4; ++nf)                     \
            acc[f][nf] = __builtin_amdgcn_mfma_f32_16x16x32_bf16(            \
                af[(K) & 1][f][hh], bfr[nf], acc[f][nf], 0, 0, 0);           \
    } }

    // prologue: buf0 staged; g(1), g(2) in flight; A(0) loaded
    GATHER(0)
    WRITEB(0)
    A_LOAD(0)
    GATHER(1)
    GATHER(2)
    asm volatile("s_waitcnt lgkmcnt(0)" ::: "memory");   // buf0 write visible

#pragma unroll
    for (int k = 0; k < NK; ++k) {
        __builtin_amdgcn_s_barrier();                    // safe to overwrite buf[(k+1)&1]
        if (k + 1 < NK) WRITEB(k + 1)
        if (k + 1 < NK) A_LOAD(k + 1)
        if (k + 3 < NK) GATHER(k + 3)
        asm volatile("s_waitcnt lgkmcnt(0)" ::: "memory"); // my ds_write done
        __builtin_amdgcn_s_barrier();                    // buf[k&1] fully written
        MFMA_STEP(k)
    }

#undef GATHER
#undef WRITEB
#undef A_LOAD
#undef MFMA_STEP

    // epilogue: C/D layout: col(n) = lane&15, row(o) = q*4 + r
#pragma unroll
    for (int f = 0; f < 2; ++f)
#pragma unroll
        for (int nf = 0; nf < 4; ++nf)
#pragma unroll
            for (int r = 0; r < 4; ++r) {
                const int o = wo * 32 + f * 16 + q * 4 + r;
                const int n = n0 + wn * 64 + nf * 16 + r16;
                out[(size_t)o * H + n] = acc[f][nf][r];
            }

    // BN partials: per-wave 16-lane shfl reduce over its 64 n, stash per-wn
    // slices in LDS, fold, one coalesced store. Zero atomics.
    float* red = (float*)sIdx;        // reuse; all gathers done; 1024 f32
    __syncthreads();
#pragma unroll
    for (int f = 0; f < 2; ++f)
#pragma unroll
        for (int r = 0; r < 4; ++r) {
            float sv = acc[f][0][r] + acc[f][1][r] + acc[f][2][r] + acc[f][3][r];
            float sq = acc[f][0][r] * acc[f][0][r] + acc[f][1][r] * acc[f][1][r]
                     + acc[f][2][r] * acc[f][2][r] + acc[f][3][r] * acc[f][3][r];
#pragma unroll
            for (int m = 1; m < 16; m <<= 1) {
                sv += __shfl_xor(sv, m, 64);
                sq += __shfl_xor(sq, m, 64);
            }
            if (r16 == 0) {
                const int o = wo * 32 + f * 16 + q * 4 + r;
                red[wn * 256 + o]       = sv;   // per-wn sum slice
                red[wn * 256 + 128 + o] = sq;   // per-wn sumsq slice
            }
        }
    __syncthreads();
    if (tid < 256)
        part[(size_t)blockIdx.x * 256 + tid] =
            red[tid] + red[256 + tid] + red[512 + tid] + red[768 + tid];
}

// ---------------------------------------------------------------------------
// Kernel 2b: fold 256 per-block partials into sums[256]. 16 atomics/address.
__global__ __launch_bounds__(256) void bn_reduce(const float* __restrict__ part,
                                                 float* __restrict__ sums) {
    const int tid = threadIdx.x;
    float s = 0.f;
    const int b0 = blockIdx.x * (NBLOCKS / 16);
    for (int b = b0; b < b0 + NBLOCKS / 16; ++b)
        s += part[(size_t)b * 256 + tid];
    atomicAdd(&sums[tid], s);
}

// ---------------------------------------------------------------------------
// Kernel 3: BN + ReLU with inline stats, float4.
__global__ __launch_bounds__(256) void bn_relu(float* __restrict__ out,
                                               const float* __restrict__ sums,
                                               const float* __restrict__ gamma,
                                               const float* __restrict__ beta) {
    const int idx = blockIdx.x * 256 + threadIdx.x;  // float4 index
    const int o = idx >> 14;                          // 16384 float4 per channel
    const float mean = sums[o] * (1.f / (float)H);
    const float var  = sums[COUT + o] * (1.f / (float)H) - mean * mean;
    const float a = gamma[o] * rsqrtf(var + 1e-5f);
    const float b = beta[o] - mean * a;
    float4* p = (float4*)out;
    float4 v = p[idx];
    v.x = fmaxf(fmaf(v.x, a, b), 0.f);
    v.y = fmaxf(fmaf(v.y, a, b), 0.f);
    v.z = fmaxf(fmaf(v.z, a, b), 0.f);
    v.w = fmaxf(fmaf(v.w, a, b), 0.f);
    p[idx] = v;
}

// ---------------------------------------------------------------------------
extern "C" void kernel_launch(void* const* d_in, const int* in_sizes, int n_in,
                              void* d_out, int out_size, void* d_ws, size_t ws_size,
                              hipStream_t stream) {
    const float* x     = (const float*)d_in[0];  // (1,64,65536,1)
    const int*   neigh = (const int*)d_in[1];    // (65536,27)
    const float* w     = (const float*)d_in[2];  // (128,64,27)
    const float* gamma = (const float*)d_in[3];
    const float* beta  = (const float*)d_in[4];
    float* out = (float*)d_out;                  // (1,128,65536,1)

    char* ws = (char*)d_ws;
    u16* xt  = (u16*)ws;                              // 8388608 B
    u16* wb  = (u16*)(ws + 8388608);                  // 442368 B
    float* sums = (float*)(ws + 8830976);             // 1024 B
    float* part = (float*)(ws + 8832000);             // 256 KB

    transpose_x<<<H / 256, 256, 0, stream>>>(x, xt);
    conv_w<<<(COUT * KTOT + 255) / 256, 256, 0, stream>>>(w, wb, sums);
    conv_mfma<<<NBLOCKS, NTHR, 0, stream>>>(xt, wb, neigh, out, part);
    bn_reduce<<<16, 256, 0, stream>>>(part, sums);
    bn_relu<<<(COUT * H / 4) / 256, 256, 0, stream>>>(out, sums, gamma, beta);
}

// Round 14
// 71.972 us; speedup vs baseline: 1.2932x; 1.2932x over previous
//
#include <hip/hip_runtime.h>

#define H 65536
#define CIN 64
#define COUT 128
#define NK 27
#define KTOT (NK*CIN)   // 1728
#define NBLK 256        // points per block; 16 waves = 8 wo x 2 wn (16o x 128n)
#define NTHR 1024
#define NBLOCKS (H/NBLK) // 256

typedef unsigned short u16;
typedef unsigned int   u32;
typedef __attribute__((ext_vector_type(8))) short short8;   // 8 bf16 (MFMA frag)
typedef __attribute__((ext_vector_type(4))) float f32x4;    // MFMA acc
typedef __attribute__((ext_vector_type(4))) unsigned int u32x4;

__device__ __forceinline__ u16 f2bf(float f) {
    u32 u = __float_as_uint(f);
    u = (u + 0x7FFFu + ((u >> 16) & 1u)) >> 16;   // RNE
    return (u16)u;
}

// ---------------------------------------------------------------------------
// Kernel 1a: x (64 x 65536 f32, c-major) -> x_t (65536 x 64 bf16, point-major)
__global__ __launch_bounds__(256) void transpose_x(const float* __restrict__ x,
                                                   u16* __restrict__ xt) {
    const int h = blockIdx.x * 256 + threadIdx.x;
    u32 pk[32];
#pragma unroll
    for (int cp = 0; cp < 32; ++cp) {
        float f0 = x[(2 * cp)     * H + h];
        float f1 = x[(2 * cp + 1) * H + h];
        pk[cp] = (u32)f2bf(f0) | ((u32)f2bf(f1) << 16);
    }
    u32x4* dst = (u32x4*)(xt + (size_t)h * CIN);
#pragma unroll
    for (int i = 0; i < 8; ++i)
        dst[i] = *(u32x4*)&pk[i * 4];
}

// ---------------------------------------------------------------------------
// Kernel 1b: w (128 x 64 x 27 f32) -> wb[o][k*64+c] bf16. Also zeroes BN sums.
__global__ __launch_bounds__(256) void conv_w(const float* __restrict__ w,
                                              u16* __restrict__ wb,
                                              float* __restrict__ sums) {
    const int tid = blockIdx.x * 256 + threadIdx.x;
    if (blockIdx.x == 0) sums[threadIdx.x] = 0.f;   // sum[128], sumsq[128]
    if (tid < COUT * KTOT) {
        const int o = tid / KTOT;
        const int rem = tid - o * KTOT;
        const int k = rem >> 6;
        const int c = rem & 63;
        wb[tid] = f2bf(w[o * KTOT + c * NK + k]);
    }
}

// ---------------------------------------------------------------------------
// Kernel 2: EXACT R12 data path (8wo x 2wn, 58us measured) with a 3-buffer
// LDS ring -> ONE barrier per k-step (was 2). WR goes 2 buffers ahead of the
// reader: MFMA(k) reads buf[k%3] (written 2 bars ago); WR(k+2) overwrites
// buf[(k-1)%3] whose readers are fenced by this body's bar; writer drains
// lgkmcnt before the next bar.
__global__ __launch_bounds__(NTHR, 4) void conv_mfma(const u16* __restrict__ xt,
                                                     const u16* __restrict__ wb,
                                                     const int* __restrict__ neigh,
                                                     float* __restrict__ out,
                                                     float* __restrict__ part) {
    __shared__ __align__(16) u16 sB[3][NBLK * CIN];  // 3 x 32 KB ring
    __shared__ u16 sIdx[NBLK * NK];                  // 13824 B (reused as f32 red)

    const int tid  = threadIdx.x;
    const int lane = tid & 63;
    const int w    = tid >> 6;        // wave 0..15
    const int wo   = w >> 1;          // o-block 0..7  (16 o each)
    const int wn   = w & 1;           // n-half 0..1   (128 n each)
    const int n0   = blockIdx.x * NBLK;

    for (int i = tid; i < NBLK * NK; i += NTHR)
        sIdx[i] = (u16)neigh[n0 * NK + i];
    __syncthreads();                   // once, before the pipeline

    const int r16 = lane & 15;
    const int q   = lane >> 4;        // 0..3
    const int kc  = q * 8;
    const int pl  = lane >> 3;        // 0..7 row-within-8
    const int cl  = lane & 7;         // 16B chunk within 128B row

    f32x4 acc[8] = {};                // [n-frag]

    u32x4  rg[2][2];                  // gather regs: g(k) in rg[k&1][it]
    short8 af[2][2];                  // A regs: A(k) in af[k&1][hh]

#define GATHER(K)                                                            \
    { _Pragma("unroll") for (int it = 0; it < 2; ++it) {                     \
        const int p_ = w * 16 + it * 8 + pl;                                 \
        const int row_ = sIdx[p_ * NK + (K)];                                \
        rg[(K) & 1][it] =                                                    \
            *(const u32x4*)(xt + (size_t)(u32)row_ * 64 + cl * 8); } }
#define WRITEB(K)                                                            \
    { _Pragma("unroll") for (int it = 0; it < 2; ++it) {                     \
        const int p_ = w * 16 + it * 8 + pl;                                 \
        *(u32x4*)(&sB[(K) % 3][p_ * 64 + ((cl ^ pl) * 8)]) = rg[(K) & 1][it]; } }
#define A_LOAD(K)                                                            \
    { _Pragma("unroll") for (int hh = 0; hh < 2; ++hh) {                     \
        const int o_ = wo * 16 + r16;                                        \
        af[(K) & 1][hh] = *(const short8*)(wb + (size_t)o_ * KTOT +          \
                                           (K) * CIN + hh * 32 + kc); } }
#define MFMA_STEP(K)                                                         \
    { _Pragma("unroll") for (int hh = 0; hh < 2; ++hh)                       \
      _Pragma("unroll") for (int g2 = 0; g2 < 2; ++g2) {                     \
        short8 bfr[4];                                                       \
        _Pragma("unroll") for (int j = 0; j < 4; ++j) {                      \
            const int nf = g2 * 4 + j;                                       \
            const int p_ = wn * 128 + nf * 16 + r16;                         \
            const int sl_ = (hh * 4 + q) ^ (p_ & 7);                         \
            bfr[j] = *(const short8*)(&sB[(K) % 3][p_ * 64 + sl_ * 8]);      \
        }                                                                    \
        _Pragma("unroll") for (int j = 0; j < 4; ++j)                        \
            acc[g2 * 4 + j] = __builtin_amdgcn_mfma_f32_16x16x32_bf16(       \
                af[(K) & 1][hh], bfr[j], acc[g2 * 4 + j], 0, 0, 0);          \
    } }

    // prologue: buf0,buf1 staged; g(2),g(3) in flight; A(0) loaded
    GATHER(0)
    GATHER(1)
    WRITEB(0)
    WRITEB(1)
    A_LOAD(0)
    GATHER(2)
    GATHER(3)
    asm volatile("s_waitcnt lgkmcnt(0)" ::: "memory");   // buf0/1 writes done

#pragma unroll
    for (int k = 0; k < NK; ++k) {
        __builtin_amdgcn_s_barrier();     // fences readers of buf[(k+2)%3]
        if (k + 2 < NK) WRITEB(k + 2)     // waits g(k+2) via counted vmcnt
        if (k + 1 < NK) A_LOAD(k + 1)
        if (k + 4 < NK) GATHER(k + 4)
        MFMA_STEP(k)                       // reads buf[k%3], written 2 bars ago
        asm volatile("s_waitcnt lgkmcnt(0)" ::: "memory"); // my WR visible pre-next-bar
    }

#undef GATHER
#undef WRITEB
#undef A_LOAD
#undef MFMA_STEP

    // epilogue: C/D layout: col(n) = lane&15, row(o) = q*4 + r
#pragma unroll
    for (int nf = 0; nf < 8; ++nf)
#pragma unroll
        for (int r = 0; r < 4; ++r) {
            const int o = wo * 16 + q * 4 + r;
            const int n = n0 + wn * 128 + nf * 16 + r16;
            out[(size_t)o * H + n] = acc[nf][r];
        }

    // BN partials: reduce this wave's 128 n per o; two wn-halves write
    // disjoint LDS slots; fold + one coalesced store. Zero atomics.
    float* red = (float*)sIdx;        // reuse; all gathers done
    __syncthreads();
#pragma unroll
    for (int r = 0; r < 4; ++r) {
        float sv = 0.f, sq = 0.f;
#pragma unroll
        for (int nf = 0; nf < 8; ++nf) {
            sv += acc[nf][r];
            sq += acc[nf][r] * acc[nf][r];
        }
#pragma unroll
        for (int m = 1; m < 16; m <<= 1) {
            sv += __shfl_xor(sv, m, 64);
            sq += __shfl_xor(sq, m, 64);
        }
        if (r16 == 0) {
            const int o = wo * 16 + q * 4 + r;
            red[wn * 256 + o]       = sv;   // sums: slots 0..127 per half
            red[wn * 256 + 128 + o] = sq;   // sumsq
        }
    }
    __syncthreads();
    if (tid < 128) {
        part[(size_t)blockIdx.x * 256 + tid]       = red[tid] + red[256 + tid];
        part[(size_t)blockIdx.x * 256 + 128 + tid] = red[128 + tid] + red[384 + tid];
    }
}

// ---------------------------------------------------------------------------
// Kernel 2b: fold 256 per-block partials into sums[256]. 16 atomics/address.
__global__ __launch_bounds__(256) void bn_reduce(const float* __restrict__ part,
                                                 float* __restrict__ sums) {
    const int tid = threadIdx.x;
    float s = 0.f;
    const int b0 = blockIdx.x * (NBLOCKS / 16);
    for (int b = b0; b < b0 + NBLOCKS / 16; ++b)
        s += part[(size_t)b * 256 + tid];
    atomicAdd(&sums[tid], s);
}

// ---------------------------------------------------------------------------
// Kernel 3: BN + ReLU with inline stats, float4.
__global__ __launch_bounds__(256) void bn_relu(float* __restrict__ out,
                                               const float* __restrict__ sums,
                                               const float* __restrict__ gamma,
                                               const float* __restrict__ beta) {
    const int idx = blockIdx.x * 256 + threadIdx.x;  // float4 index
    const int o = idx >> 14;                          // 16384 float4 per channel
    const float mean = sums[o] * (1.f / (float)H);
    const float var  = sums[COUT + o] * (1.f / (float)H) - mean * mean;
    const float a = gamma[o] * rsqrtf(var + 1e-5f);
    const float b = beta[o] - mean * a;
    float4* p = (float4*)out;
    float4 v = p[idx];
    v.x = fmaxf(fmaf(v.x, a, b), 0.f);
    v.y = fmaxf(fmaf(v.y, a, b), 0.f);
    v.z = fmaxf(fmaf(v.z, a, b), 0.f);
    v.w = fmaxf(fmaf(v.w, a, b), 0.f);
    p[idx] = v;
}

// ---------------------------------------------------------------------------
extern "C" void kernel_launch(void* const* d_in, const int* in_sizes, int n_in,
                              void* d_out, int out_size, void* d_ws, size_t ws_size,
                              hipStream_t stream) {
    const float* x     = (const float*)d_in[0];  // (1,64,65536,1)
    const int*   neigh = (const int*)d_in[1];    // (65536,27)
    const float* w     = (const float*)d_in[2];  // (128,64,27)
    const float* gamma = (const float*)d_in[3];
    const float* beta  = (const float*)d_in[4];
    float* out = (float*)d_out;                  // (1,128,65536,1)

    char* ws = (char*)d_ws;
    u16* xt  = (u16*)ws;                              // 8388608 B
    u16* wb  = (u16*)(ws + 8388608);                  // 442368 B
    float* sums = (float*)(ws + 8830976);             // 1024 B
    float* part = (float*)(ws + 8832000);             // 256 KB

    transpose_x<<<H / 256, 256, 0, stream>>>(x, xt);
    conv_w<<<(COUT * KTOT + 255) / 256, 256, 0, stream>>>(w, wb, sums);
    conv_mfma<<<NBLOCKS, NTHR, 0, stream>>>(xt, wb, neigh, out, part);
    bn_reduce<<<16, 256, 0, stream>>>(part, sums);
    bn_relu<<<(COUT * H / 4) / 256, 256, 0, stream>>>(out, sums, gamma, beta);
}